// Round 6
// baseline (75.678 us; speedup 1.0000x reference)
//
#include <hip/hip_runtime.h>
#include <hip/hip_bf16.h>

typedef unsigned short ushort_t;
typedef __attribute__((ext_vector_type(8))) short short8;
typedef __attribute__((ext_vector_type(4))) float floatx4;
typedef __attribute__((ext_vector_type(2))) float floatx2;
typedef __attribute__((ext_vector_type(4))) int intx4;

#define SIG_CH 584
#define KPAD   608      // 19 * 32
#define NPROJ  128
#define ASTRIDE 616     // bf16 elems; 16B-aligned rows, bank-uniform
#define TLEN   4096
#define NWIN   32768    // B*T
#define WPB    32       // windows per block -> 41 KB LDS -> 3 blocks/CU
#define TSTR   40       // transposed-increment row stride (floats)

__device__ __forceinline__ ushort_t f2bf(float f) {
    unsigned int v; __builtin_memcpy(&v, &f, 4);
    v += 0x7fffu + ((v >> 16) & 1u);   // round-to-nearest-even
    return (ushort_t)(v >> 16);
}

// Pack W (584x128 fp32, row-major) into bf16 (kb, n, kk), K zero-padded to 608.
__global__ void pack_w_kernel(const float* __restrict__ w, ushort_t* __restrict__ wp) {
    int idx = blockIdx.x * 256 + threadIdx.x;
    if (idx >= KPAD * NPROJ) return;
    int n = idx & (NPROJ - 1);
    int c = idx >> 7;
    ushort_t v = 0;
    if (c < SIG_CH) v = f2bf(w[c * NPROJ + n]);
    wp[((size_t)(c >> 3) * NPROJ + n) * 8 + (c & 7)] = v;
}

__launch_bounds__(256, 3)
__global__ void sig_gemm_kernel(const float* __restrict__ x,
                                const ushort_t* __restrict__ wp,
                                const float* __restrict__ bias,
                                float* __restrict__ out) {
    __shared__ float    s_dinc[WPB + 6][8];     // 38 increment rows, row-major
    __shared__ float    s_dincT[8][TSTR];       // transposed: s_dincT[k][row]
    __shared__ ushort_t s_A[WPB][ASTRIDE];      // bf16 signature tile (GEMM A)

    const int tid  = threadIdx.x;
    const int blk  = blockIdx.x;                // 1024 blocks
    const int g0   = blk * WPB;                 // first global window index
    const int b    = g0 >> 12;                  // / 4096
    const int t0   = g0 & (TLEN - 1);

    // ---- phase 0: increments straight from x into BOTH LDS layouts ----
    if (tid < (WPB + 6) * 2) {
        const int s    = tid >> 1;              // increment row 0..37 (ta = t0-7+s)
        const int half = tid & 1;
        const int ta   = t0 - 7 + s;
        floatx4 d4 = floatx4{0.f, 0.f, 0.f, 0.f};
        if (ta >= 0) {
            const float* p = x + ((size_t)b * TLEN + ta) * 8 + half * 4;
            const floatx4 a0 = *(const floatx4*)p;
            const floatx4 a1 = *(const floatx4*)(p + 8);
            d4 = a1 - a0;
        }
        *(floatx4*)(&s_dinc[s][half * 4]) = d4;
        #pragma unroll
        for (int l = 0; l < 4; ++l) s_dincT[half * 4 + l][s] = d4[l];
    }
    // zero A pad columns [584, 616)
    for (int idx = tid; idx < WPB * 32; idx += 256) {
        int r = idx >> 5, c = SIG_CH + (idx & 31);
        s_A[r][c] = 0;
    }
    __syncthreads();

    // ---- phase 1: signatures (1 wave = 8 windows; lane (i,j) owns s2[i][j], s3[i][j][:]) ----
    const int wv   = tid >> 6;     // wave 0..3
    const int lane = tid & 63;
    const int li   = lane >> 3;    // i
    const int lj   = lane & 7;     // j
    const int w0   = wv * 8;

    // per-lane di/dj strips: rows w0..w0+13 of the li-th / lj-th increment component
    float dis[14], djs[14];
    {
        const float* pi = &s_dincT[li][w0];
        const float* pj = &s_dincT[lj][w0];
        *(floatx4*)&dis[0] = *(const floatx4*)(pi);
        *(floatx4*)&dis[4] = *(const floatx4*)(pi + 4);
        *(floatx4*)&dis[8] = *(const floatx4*)(pi + 8);
        *(floatx2*)&dis[12] = *(const floatx2*)(pi + 12);
        *(floatx4*)&djs[0] = *(const floatx4*)(pj);
        *(floatx4*)&djs[4] = *(const floatx4*)(pj + 4);
        *(floatx4*)&djs[8] = *(const floatx4*)(pj + 8);
        *(floatx2*)&djs[12] = *(const floatx2*)(pj + 12);
    }

    // rotating register file of the 7 active increment rows (wave-uniform values)
    float rows[7][8];
    #pragma unroll
    for (int r = 0; r < 6; ++r) {
        *(floatx4*)&rows[r][0] = *(const floatx4*)&s_dinc[w0 + r][0];
        *(floatx4*)&rows[r][4] = *(const floatx4*)&s_dinc[w0 + r][4];
    }

    #pragma unroll
    for (int ww = 0; ww < 8; ++ww) {
        const int w = w0 + ww;
        {
            const int slot = (ww + 6) % 7;
            *(floatx4*)&rows[slot][0] = *(const floatx4*)&s_dinc[w + 6][0];
            *(floatx4*)&rows[slot][4] = *(const floatx4*)&s_dinc[w + 6][4];
        }
        float h = 0.f, g = 0.f, s2 = 0.f;
        float s3[8] = {0.f, 0.f, 0.f, 0.f, 0.f, 0.f, 0.f, 0.f};
        #pragma unroll
        for (int st = 0; st < 7; ++st) {
            const float* d = rows[(ww + st) % 7];
            const float di = dis[ww + st];
            const float dj = djs[ww + st];
            // c3 = s2_old + 0.5*s1i_old*dj + di*dj/6 ; s2' = s2_old + s1i_old*dj + 0.5*di*dj
            const float c3 = fmaf(dj, fmaf(0.166666667f, di, 0.5f * h), s2);
            s2 = fmaf(dj, fmaf(0.5f, di, h), s2);
            #pragma unroll
            for (int k = 0; k < 8; ++k)
                s3[k] = fmaf(c3, d[k], s3[k]);
            h += di;
            g += dj;
        }
        // write sig row: [s1(8) | s2(64) | s3(512)] as bf16
        union { ushort_t u[8]; intx4 v; } pk;
        #pragma unroll
        for (int k = 0; k < 8; ++k) pk.u[k] = f2bf(s3[k]);
        *(intx4*)(&s_A[w][72 + lane * 8]) = pk.v;   // 16B-aligned
        s_A[w][8 + lane] = f2bf(s2);
        if (lane < 8) s_A[w][lane] = f2bf(g);       // lane<8 has i=0, j=lane -> s1[j]
    }
    __syncthreads();

    // ---- phase 2: GEMM 32x128 @ K=608, wave = 32-col n-slice over all 32 rows ----
    const int lrow  = lane & 15;   // A row within 16-tile / output col within fragment
    const int kgrp  = lane >> 4;   // k-group (k = kgrp*8 + j)
    const int ncol0 = wv * 32 + lrow;

    floatx4 acc[2][2];
    #pragma unroll
    for (int mt = 0; mt < 2; ++mt) {
        acc[mt][0] = floatx4{0.f, 0.f, 0.f, 0.f};
        acc[mt][1] = floatx4{0.f, 0.f, 0.f, 0.f};
    }

    for (int kc = 0; kc < 19; ++kc) {
        const int kb = kc * 4 + kgrp;
        const short8 b0 = *(const short8*)(wp + ((size_t)kb * NPROJ + ncol0) * 8);
        const short8 b1 = *(const short8*)(wp + ((size_t)kb * NPROJ + ncol0 + 16) * 8);
        #pragma unroll
        for (int mt = 0; mt < 2; ++mt) {
            const short8 af = *(const short8*)(&s_A[mt * 16 + lrow][kc * 32 + kgrp * 8]);
            acc[mt][0] = __builtin_amdgcn_mfma_f32_16x16x32_bf16(af, b0, acc[mt][0], 0, 0, 0);
            acc[mt][1] = __builtin_amdgcn_mfma_f32_16x16x32_bf16(af, b1, acc[mt][1], 0, 0, 0);
        }
    }

    const float bias0 = bias[ncol0];
    const float bias1 = bias[ncol0 + 16];
    #pragma unroll
    for (int mt = 0; mt < 2; ++mt) {
        #pragma unroll
        for (int r = 0; r < 4; ++r) {
            const int row = g0 + mt * 16 + kgrp * 4 + r;   // C/D: row = quad*4 + reg
            out[(size_t)row * NPROJ + ncol0]      = acc[mt][0][r] + bias0;
            out[(size_t)row * NPROJ + ncol0 + 16] = acc[mt][1][r] + bias1;
        }
    }
}

extern "C" void kernel_launch(void* const* d_in, const int* in_sizes, int n_in,
                              void* d_out, int out_size, void* d_ws, size_t ws_size,
                              hipStream_t stream) {
    const float* x  = (const float*)d_in[0];   // (8,4096,8) fp32
    const float* w  = (const float*)d_in[1];   // (584,128) fp32
    const float* bp = (const float*)d_in[2];   // (128,) fp32
    ushort_t* wp    = (ushort_t*)d_ws;         // 155,648 B
    float* out = (float*)d_out;                // (8,4096,128) fp32

    hipLaunchKernelGGL(pack_w_kernel, dim3((KPAD * NPROJ + 255) / 256), dim3(256), 0, stream,
                       w, wp);
    hipLaunchKernelGGL(sig_gemm_kernel, dim3(NWIN / WPB), dim3(256), 0, stream,
                       x, wp, bp, out);
}